// Round 1
// baseline (4833.865 us; speedup 1.0000x reference)
//
#include <hip/hip_runtime.h>

#define B_ 64
#define T_ 4096
#define D_ 256
#define N_ 64

// ---------------- misc: lens + trans copy ----------------
__global__ __launch_bounds__(64) void k_misc(const unsigned char* __restrict__ mask,
                                             const float* __restrict__ trans,
                                             float* __restrict__ out_lens,
                                             float* __restrict__ out_trans,
                                             int* __restrict__ lens_i) {
  int blk = blockIdx.x, lane = threadIdx.x;
  if (blk < B_) {
    // detect bool-as-u8 vs int32 storage: all-ones mask -> u8 gives 4, i32 gives 1
    int probe = (int)mask[0] + (int)mask[1] + (int)mask[2] + (int)mask[3];
    int cnt = 0;
    if (probe >= 2) {
      const unsigned char* row = mask + (size_t)blk * T_;
      for (int i = lane; i < T_; i += 64) cnt += row[i] ? 1 : 0;
    } else {
      const int* rowi = (const int*)mask + (size_t)blk * T_;
      for (int i = lane; i < T_; i += 64) cnt += rowi[i] ? 1 : 0;
    }
    #pragma unroll
    for (int off = 32; off > 0; off >>= 1) cnt += __shfl_down(cnt, off, 64);
    if (lane == 0) { out_lens[blk] = (float)cnt; lens_i[blk] = cnt; }
  } else {
    int base = (blk - B_) * 1024;
    for (int i = lane; i < 1024; i += 64) out_trans[base + i] = trans[base + i];
  }
}

// ---------------- projection: pot = x@W + b (+ boundaries) ----------------
// one wave handles 16 rows x 64 cols; lane = col. W column chunk in 64 VGPRs,
// x read as uniform float4 loads (4 FMA per 16B load).
__global__ __launch_bounds__(256) void k_gemm(const float* __restrict__ x,
                                              const float* __restrict__ W,
                                              const float* __restrict__ bias,
                                              const float* __restrict__ lb,
                                              const float* __restrict__ rb,
                                              float* __restrict__ pot) {
  int wave = (blockIdx.x * blockDim.x + threadIdx.x) >> 6;
  int lane = threadIdx.x & 63;
  long row0 = (long)wave * 16;

  float bv = bias[lane];
  float lbv = lb[lane];
  float rbv = rb[lane];

  float acc[16];
  #pragma unroll
  for (int r = 0; r < 16; ++r) {
    int t = (int)((row0 + r) & (T_ - 1));
    float a = bv;
    if (t == 0)      a += lbv;
    if (t == T_ - 1) a += rbv;
    acc[r] = a;
  }

  #pragma unroll
  for (int c = 0; c < 4; ++c) {
    int d0 = c * 64;
    float w[64];
    #pragma unroll
    for (int k = 0; k < 64; ++k) w[k] = W[(d0 + k) * N_ + lane];
    #pragma unroll
    for (int r = 0; r < 16; ++r) {
      const float4* xr = reinterpret_cast<const float4*>(x + (row0 + r) * D_ + d0);
      #pragma unroll
      for (int k4 = 0; k4 < 16; ++k4) {
        float4 xv = xr[k4];
        acc[r] += xv.x * w[k4 * 4 + 0];
        acc[r] += xv.y * w[k4 * 4 + 1];
        acc[r] += xv.z * w[k4 * 4 + 2];
        acc[r] += xv.w * w[k4 * 4 + 3];
      }
    }
  }

  #pragma unroll
  for (int r = 0; r < 16; ++r) pot[(row0 + r) * N_ + lane] = acc[r];
}

// ---------------- viterbi forward: 1 wave per batch, lane = cur ----------------
__global__ __launch_bounds__(64) void k_fwd(const float* __restrict__ pot,
                                            const float* __restrict__ trans,
                                            const int* __restrict__ lens_i,
                                            unsigned char* __restrict__ bp,
                                            float* __restrict__ fstate) {
  int b = blockIdx.x;
  int lane = threadIdx.x;

  __shared__ float4 st4v[16];
  float* st = (float*)st4v;

  // trans column for this lane: tcol[prev] = trans[prev][lane]
  float tcol[64];
  #pragma unroll
  for (int p = 0; p < 64; ++p) tcol[p] = trans[p * N_ + lane];

  const float* pb = pot + (size_t)b * T_ * N_;
  int len_b = lens_i[b];

  float state = pb[lane];           // t=0 (left boundary already folded in)
  st[lane] = state;
  __builtin_amdgcn_wave_barrier();

  // 2-deep pot prefetch
  float pn1 = pb[1 * N_ + lane];
  float pn2 = pb[2 * N_ + lane];

  unsigned char* bpb = bp + (size_t)b * T_ * N_;

  for (int t = 1; t < T_; ++t) {
    float pot_t = pn1;
    pn1 = pn2;
    if (t + 2 < T_) pn2 = pb[(t + 2) * N_ + lane];

    float best = -3.4e38f;
    int bpi = 0;
    #pragma unroll
    for (int g = 0; g < 16; ++g) {
      float4 s4 = st4v[g];
      float c0 = s4.x + tcol[4 * g + 0]; if (c0 > best) { best = c0; bpi = 4 * g + 0; }
      float c1 = s4.y + tcol[4 * g + 1]; if (c1 > best) { best = c1; bpi = 4 * g + 1; }
      float c2 = s4.z + tcol[4 * g + 2]; if (c2 > best) { best = c2; bpi = 4 * g + 2; }
      float c3 = s4.w + tcol[4 * g + 3]; if (c3 > best) { best = c3; bpi = 4 * g + 3; }
    }

    float ns = pot_t + best;
    state = (t < len_b) ? ns : state;   // carry past length

    bpb[(size_t)t * N_ + lane] = (unsigned char)bpi;

    __builtin_amdgcn_wave_barrier();
    st[lane] = state;                    // single wave: DS pipe is in-order per wave
    __builtin_amdgcn_wave_barrier();
  }

  fstate[b * N_ + lane] = state;
}

// ---------------- backtrace: serial chain with 16-deep row prefetch ----------------
__global__ __launch_bounds__(64) void k_bwd(const unsigned char* __restrict__ bp,
                                            const float* __restrict__ fstate,
                                            const int* __restrict__ lens_i,
                                            float* __restrict__ decoded) {
  int b = blockIdx.x, lane = threadIdx.x;

  __shared__ float fv[64];
  __shared__ int sh_tag;
  fv[lane] = fstate[b * N_ + lane];
  __syncthreads();
  if (lane == 0) {
    float best = fv[0]; int tg = 0;
    for (int i = 1; i < 64; ++i) if (fv[i] > best) { best = fv[i]; tg = i; }  // first max
    sh_tag = tg;
  }
  __syncthreads();
  int last_tag = sh_tag;
  int len_b = lens_i[b];

  const unsigned char* bpb = bp + (size_t)b * T_ * N_;
  float* dec = decoded + (size_t)b * T_;

  int tag = last_tag;
  if (lane == 0) dec[T_ - 1] = (float)last_tag;

  // rows consumed: k = T-1 .. 1 ; decoded[t=k-1] = tag_{k-1}
  const int G = 16;
  int bufA[G], bufB[G];
  const int k0 = T_ - 1;          // 4095
  #pragma unroll
  for (int i = 0; i < G; ++i) bufA[i] = (int)bpb[(size_t)(k0 - i) * N_ + lane];

  const int nrows = T_ - 1;       // 4095
  const int groups = nrows / G;   // 255 full groups, 15-row tail

  for (int g = 0; g < groups; ++g) {
    int kn = k0 - G * (g + 1);
    #pragma unroll
    for (int i = 0; i < G; ++i)
      bufB[i] = (kn - i >= 1) ? (int)bpb[(size_t)(kn - i) * N_ + lane] : 0;

    int kbase = k0 - G * g;
    #pragma unroll
    for (int i = 0; i < G; ++i) {
      int k = kbase - i;
      int prev = __shfl(bufA[i], tag, 64);
      int t = k - 1;
      tag = (t < len_b - 1) ? prev : last_tag;
      if (lane == 0) dec[t] = (float)tag;
    }
    #pragma unroll
    for (int i = 0; i < G; ++i) bufA[i] = bufB[i];
  }

  // tail rows: k = k0 - G*groups .. 1
  int kbase = k0 - G * groups;
  #pragma unroll
  for (int i = 0; i < G; ++i) {
    int k = kbase - i;
    if (k >= 1) {
      int prev = __shfl(bufA[i], tag, 64);
      int t = k - 1;
      tag = (t < len_b - 1) ? prev : last_tag;
      if (lane == 0) dec[t] = (float)tag;
    }
  }
}

extern "C" void kernel_launch(void* const* d_in, const int* in_sizes, int n_in,
                              void* d_out, int out_size, void* d_ws, size_t ws_size,
                              hipStream_t stream) {
  const float* x            = (const float*)d_in[0];
  const unsigned char* mask = (const unsigned char*)d_in[1];
  const float* W            = (const float*)d_in[2];
  const float* bias         = (const float*)d_in[3];
  const float* trans        = (const float*)d_in[4];
  const float* lb           = (const float*)d_in[5];
  const float* rb           = (const float*)d_in[6];

  float* out         = (float*)d_out;
  float* out_decoded = out;                                   // B*T
  float* out_pot     = out + (size_t)B_ * T_;                 // B*T*N
  float* out_lens    = out_pot + (size_t)B_ * T_ * N_;        // B
  float* out_trans   = out_lens + B_;                         // N*N

  unsigned char* bp = (unsigned char*)d_ws;                               // B*T*N bytes
  float* fstate     = (float*)((char*)d_ws + (size_t)B_ * T_ * N_);       // B*N floats
  int*   lens_i     = (int*)((char*)d_ws + (size_t)B_ * T_ * N_ + (size_t)B_ * N_ * 4);

  k_misc<<<68, 64, 0, stream>>>(mask, trans, out_lens, out_trans, lens_i);
  k_gemm<<<(B_ * T_) / 64, 256, 0, stream>>>(x, W, bias, lb, rb, out_pot);
  k_fwd<<<B_, 64, 0, stream>>>(out_pot, trans, lens_i, bp, fstate);
  k_bwd<<<B_, 64, 0, stream>>>(bp, fstate, lens_i, out_decoded);
}

// Round 2
// 2013.704 us; speedup vs baseline: 2.4005x; 2.4005x over previous
//
#include <hip/hip_runtime.h>

#define B_ 64
#define T_ 4096
#define D_ 256
#define N_ 64

typedef float f32x16 __attribute__((ext_vector_type(16)));

// ---------------- misc: lens + trans copy ----------------
__global__ __launch_bounds__(64) void k_misc(const unsigned char* __restrict__ mask,
                                             const float* __restrict__ trans,
                                             float* __restrict__ out_lens,
                                             float* __restrict__ out_trans,
                                             int* __restrict__ lens_i) {
  int blk = blockIdx.x, lane = threadIdx.x;
  if (blk < B_) {
    int probe = (int)mask[0] + (int)mask[1] + (int)mask[2] + (int)mask[3];
    int cnt = 0;
    if (probe >= 2) {
      const unsigned char* row = mask + (size_t)blk * T_;
      for (int i = lane; i < T_; i += 64) cnt += row[i] ? 1 : 0;
    } else {
      const int* rowi = (const int*)mask + (size_t)blk * T_;
      for (int i = lane; i < T_; i += 64) cnt += rowi[i] ? 1 : 0;
    }
    #pragma unroll
    for (int off = 32; off > 0; off >>= 1) cnt += __shfl_down(cnt, off, 64);
    if (lane == 0) { out_lens[blk] = (float)cnt; lens_i[blk] = cnt; }
  } else {
    int base = (blk - B_) * 1024;
    for (int i = lane; i < 1024; i += 64) out_trans[base + i] = trans[base + i];
  }
}

// ---------------- projection: pot = x@W + b (+ boundaries) ----------------
// one wave = 16 rows x 64 cols; lane = col. x rows read via wave-uniform
// (readfirstlane) pointer -> scalar loads; W column chunk in 64 VGPRs.
// Accumulation order identical to round-1 (k ascending, single chain).
__global__ __launch_bounds__(256, 4) void k_gemm(const float* __restrict__ x,
                                                 const float* __restrict__ W,
                                                 const float* __restrict__ bias,
                                                 const float* __restrict__ lb,
                                                 const float* __restrict__ rb,
                                                 float* __restrict__ pot) {
  int wave = (blockIdx.x * blockDim.x + threadIdx.x) >> 6;
  int wave_u = __builtin_amdgcn_readfirstlane(wave);
  int lane = threadIdx.x & 63;
  long row0 = (long)wave_u * 16;

  float bv = bias[lane];
  float lbv = lb[lane];
  float rbv = rb[lane];

  float acc[16];
  #pragma unroll
  for (int r = 0; r < 16; ++r) {
    int t = (int)((row0 + r) & (T_ - 1));
    float a = bv;
    if (t == 0)      a += lbv;
    if (t == T_ - 1) a += rbv;
    acc[r] = a;
  }

  const float* xb = x + (size_t)row0 * D_;

  #pragma unroll
  for (int c = 0; c < 4; ++c) {
    int d0 = c * 64;
    float w[64];
    #pragma unroll
    for (int k = 0; k < 64; ++k) w[k] = W[(d0 + k) * N_ + lane];
    #pragma unroll
    for (int r = 0; r < 16; ++r) {
      const f32x16* xr = reinterpret_cast<const f32x16*>(xb + r * D_ + d0);
      #pragma unroll
      for (int q = 0; q < 4; ++q) {
        f32x16 xv = xr[q];
        #pragma unroll
        for (int j = 0; j < 16; ++j) acc[r] += xv[j] * w[q * 16 + j];
      }
    }
  }

  #pragma unroll
  for (int r = 0; r < 16; ++r) pot[(row0 + r) * N_ + lane] = acc[r];
}

// ---------------- phase 1: forward values only (max3 tree), store all states --------
__global__ __launch_bounds__(64, 1) void k_fwd_states(const float* __restrict__ pot,
                                                      const float* __restrict__ trans,
                                                      const int* __restrict__ lens_i,
                                                      float* __restrict__ states,
                                                      float* __restrict__ fstate) {
  int b = blockIdx.x, lane = threadIdx.x;
  __shared__ float4 st4v[16];
  float* st = (float*)st4v;

  float tcol[64];
  #pragma unroll
  for (int p = 0; p < 64; ++p) tcol[p] = trans[p * N_ + lane];

  const float* pb = pot + (size_t)b * T_ * N_;
  float* sb = states + (size_t)b * T_ * N_;
  int len_b = lens_i[b];

  float state = pb[lane];
  st[lane] = state;
  sb[lane] = state;                       // states[t=0]
  __builtin_amdgcn_wave_barrier();

  float pn[4];
  pn[0] = pb[1 * N_ + lane];
  pn[1] = pb[2 * N_ + lane];
  pn[2] = pb[3 * N_ + lane];
  pn[3] = pb[4 * N_ + lane];

  for (int t = 1; t < T_; ++t) {
    float pot_t = pn[0];
    pn[0] = pn[1]; pn[1] = pn[2]; pn[2] = pn[3];
    int tp = t + 4; if (tp > T_ - 1) tp = T_ - 1;
    pn[3] = pb[(size_t)tp * N_ + lane];

    float c[64];
    #pragma unroll
    for (int g = 0; g < 16; ++g) {
      float4 s4 = st4v[g];
      c[4 * g + 0] = s4.x + tcol[4 * g + 0];
      c[4 * g + 1] = s4.y + tcol[4 * g + 1];
      c[4 * g + 2] = s4.z + tcol[4 * g + 2];
      c[4 * g + 3] = s4.w + tcol[4 * g + 3];
    }
    // exact fp32 max tree (associative): 64 -> 22 -> 8 -> 3 -> 1, max3-friendly
    float m1[22];
    #pragma unroll
    for (int i = 0; i < 21; ++i) m1[i] = fmaxf(fmaxf(c[3 * i], c[3 * i + 1]), c[3 * i + 2]);
    m1[21] = c[63];
    float m2[8];
    #pragma unroll
    for (int i = 0; i < 7; ++i) m2[i] = fmaxf(fmaxf(m1[3 * i], m1[3 * i + 1]), m1[3 * i + 2]);
    m2[7] = m1[21];
    float m3a = fmaxf(fmaxf(m2[0], m2[1]), m2[2]);
    float m3b = fmaxf(fmaxf(m2[3], m2[4]), m2[5]);
    float m3c = fmaxf(m2[6], m2[7]);
    float best = fmaxf(fmaxf(m3a, m3b), m3c);

    float ns = pot_t + best;
    state = (t < len_b) ? ns : state;
    sb[(size_t)t * N_ + lane] = state;

    __builtin_amdgcn_wave_barrier();
    st[lane] = state;                     // single wave: DS pipe in-order
    __builtin_amdgcn_wave_barrier();
  }
  fstate[b * N_ + lane] = state;
}

// ---------------- phase 2: backpointers, fully parallel over (b,t) ----------------
__global__ __launch_bounds__(64, 2) void k_bp(const float* __restrict__ states,
                                              const float* __restrict__ trans,
                                              unsigned char* __restrict__ bp) {
  unsigned idx = blockIdx.x;              // 0 .. B*(T-1)-1
  unsigned b = idx / (unsigned)(T_ - 1);
  unsigned t = 1u + idx - b * (unsigned)(T_ - 1);
  int lane = threadIdx.x;

  float tcol[64];
  #pragma unroll
  for (int p = 0; p < 64; ++p) tcol[p] = trans[p * N_ + lane];

  const float* srow = states + ((size_t)b * T_ + (t - 1)) * N_;  // wave-uniform base

  float c[64];
  #pragma unroll
  for (int p = 0; p < 64; ++p) c[p] = srow[p] + tcol[p];

  // first-index argmax tree: right wins only on strictly-greater
  float v1[32]; int i1[32];
  #pragma unroll
  for (int i = 0; i < 32; ++i) {
    bool g = c[2 * i + 1] > c[2 * i];
    v1[i] = g ? c[2 * i + 1] : c[2 * i];
    i1[i] = g ? 2 * i + 1 : 2 * i;
  }
  float v2[16]; int i2[16];
  #pragma unroll
  for (int i = 0; i < 16; ++i) {
    bool g = v1[2 * i + 1] > v1[2 * i];
    v2[i] = g ? v1[2 * i + 1] : v1[2 * i];
    i2[i] = g ? i1[2 * i + 1] : i1[2 * i];
  }
  float v3[8]; int i3[8];
  #pragma unroll
  for (int i = 0; i < 8; ++i) {
    bool g = v2[2 * i + 1] > v2[2 * i];
    v3[i] = g ? v2[2 * i + 1] : v2[2 * i];
    i3[i] = g ? i2[2 * i + 1] : i2[2 * i];
  }
  float v4[4]; int i4[4];
  #pragma unroll
  for (int i = 0; i < 4; ++i) {
    bool g = v3[2 * i + 1] > v3[2 * i];
    v4[i] = g ? v3[2 * i + 1] : v3[2 * i];
    i4[i] = g ? i3[2 * i + 1] : i3[2 * i];
  }
  bool ga = v4[1] > v4[0];
  float va = ga ? v4[1] : v4[0]; int ia = ga ? i4[1] : i4[0];
  bool gb = v4[3] > v4[2];
  float vb = gb ? v4[3] : v4[2]; int ib = gb ? i4[3] : i4[2];
  int bpi = (vb > va) ? ib : ia;

  bp[((size_t)b * T_ + t) * N_ + lane] = (unsigned char)bpi;
}

// ---------------- fallback: fused forward (tree argmax), if ws too small ------------
__global__ __launch_bounds__(64, 1) void k_fwd_fused(const float* __restrict__ pot,
                                                     const float* __restrict__ trans,
                                                     const int* __restrict__ lens_i,
                                                     unsigned char* __restrict__ bp,
                                                     float* __restrict__ fstate) {
  int b = blockIdx.x, lane = threadIdx.x;
  __shared__ float4 st4v[16];
  float* st = (float*)st4v;

  float tcol[64];
  #pragma unroll
  for (int p = 0; p < 64; ++p) tcol[p] = trans[p * N_ + lane];

  const float* pb = pot + (size_t)b * T_ * N_;
  int len_b = lens_i[b];
  unsigned char* bpb = bp + (size_t)b * T_ * N_;

  float state = pb[lane];
  st[lane] = state;
  __builtin_amdgcn_wave_barrier();

  float pn[4];
  pn[0] = pb[1 * N_ + lane];
  pn[1] = pb[2 * N_ + lane];
  pn[2] = pb[3 * N_ + lane];
  pn[3] = pb[4 * N_ + lane];

  for (int t = 1; t < T_; ++t) {
    float pot_t = pn[0];
    pn[0] = pn[1]; pn[1] = pn[2]; pn[2] = pn[3];
    int tp = t + 4; if (tp > T_ - 1) tp = T_ - 1;
    pn[3] = pb[(size_t)tp * N_ + lane];

    float c[64];
    #pragma unroll
    for (int g = 0; g < 16; ++g) {
      float4 s4 = st4v[g];
      c[4 * g + 0] = s4.x + tcol[4 * g + 0];
      c[4 * g + 1] = s4.y + tcol[4 * g + 1];
      c[4 * g + 2] = s4.z + tcol[4 * g + 2];
      c[4 * g + 3] = s4.w + tcol[4 * g + 3];
    }
    float v1[32]; int i1[32];
    #pragma unroll
    for (int i = 0; i < 32; ++i) {
      bool g = c[2 * i + 1] > c[2 * i];
      v1[i] = g ? c[2 * i + 1] : c[2 * i];
      i1[i] = g ? 2 * i + 1 : 2 * i;
    }
    float v2[16]; int i2[16];
    #pragma unroll
    for (int i = 0; i < 16; ++i) {
      bool g = v1[2 * i + 1] > v1[2 * i];
      v2[i] = g ? v1[2 * i + 1] : v1[2 * i];
      i2[i] = g ? i1[2 * i + 1] : i1[2 * i];
    }
    float v3[8]; int i3[8];
    #pragma unroll
    for (int i = 0; i < 8; ++i) {
      bool g = v2[2 * i + 1] > v2[2 * i];
      v3[i] = g ? v2[2 * i + 1] : v2[2 * i];
      i3[i] = g ? i2[2 * i + 1] : i2[2 * i];
    }
    float v4[4]; int i4[4];
    #pragma unroll
    for (int i = 0; i < 4; ++i) {
      bool g = v3[2 * i + 1] > v3[2 * i];
      v4[i] = g ? v3[2 * i + 1] : v3[2 * i];
      i4[i] = g ? i3[2 * i + 1] : i3[2 * i];
    }
    bool ga = v4[1] > v4[0];
    float va = ga ? v4[1] : v4[0]; int ia = ga ? i4[1] : i4[0];
    bool gb = v4[3] > v4[2];
    float vb = gb ? v4[3] : v4[2]; int ib = gb ? i4[3] : i4[2];
    bool gf = vb > va;
    float best = gf ? vb : va;
    int bpi = gf ? ib : ia;

    bpb[(size_t)t * N_ + lane] = (unsigned char)bpi;

    float ns = pot_t + best;
    state = (t < len_b) ? ns : state;

    __builtin_amdgcn_wave_barrier();
    st[lane] = state;
    __builtin_amdgcn_wave_barrier();
  }
  fstate[b * N_ + lane] = state;
}

// ---------------- backtrace: serial chain with 16-deep row prefetch ----------------
__global__ __launch_bounds__(64, 1) void k_bwd(const unsigned char* __restrict__ bp,
                                               const float* __restrict__ fstate,
                                               const int* __restrict__ lens_i,
                                               float* __restrict__ decoded) {
  int b = blockIdx.x, lane = threadIdx.x;

  __shared__ float fv[64];
  __shared__ int sh_tag;
  fv[lane] = fstate[b * N_ + lane];
  __syncthreads();
  if (lane == 0) {
    float best = fv[0]; int tg = 0;
    for (int i = 1; i < 64; ++i) if (fv[i] > best) { best = fv[i]; tg = i; }
    sh_tag = tg;
  }
  __syncthreads();
  int last_tag = sh_tag;
  int len_b = lens_i[b];

  const unsigned char* bpb = bp + (size_t)b * T_ * N_;
  float* dec = decoded + (size_t)b * T_;

  int tag = last_tag;
  if (lane == 0) dec[T_ - 1] = (float)last_tag;

  const int G = 16;
  int bufA[G], bufB[G];
  const int k0 = T_ - 1;
  #pragma unroll
  for (int i = 0; i < G; ++i) bufA[i] = (int)bpb[(size_t)(k0 - i) * N_ + lane];

  const int nrows = T_ - 1;
  const int groups = nrows / G;

  for (int g = 0; g < groups; ++g) {
    int kn = k0 - G * (g + 1);
    #pragma unroll
    for (int i = 0; i < G; ++i)
      bufB[i] = (kn - i >= 1) ? (int)bpb[(size_t)(kn - i) * N_ + lane] : 0;

    int kbase = k0 - G * g;
    #pragma unroll
    for (int i = 0; i < G; ++i) {
      int k = kbase - i;
      int prev = __shfl(bufA[i], tag, 64);
      int t = k - 1;
      tag = (t < len_b - 1) ? prev : last_tag;
      if (lane == 0) dec[t] = (float)tag;
    }
    #pragma unroll
    for (int i = 0; i < G; ++i) bufA[i] = bufB[i];
  }

  int kbase = k0 - G * groups;
  #pragma unroll
  for (int i = 0; i < G; ++i) {
    int k = kbase - i;
    if (k >= 1) {
      int prev = __shfl(bufA[i], tag, 64);
      int t = k - 1;
      tag = (t < len_b - 1) ? prev : last_tag;
      if (lane == 0) dec[t] = (float)tag;
    }
  }
}

extern "C" void kernel_launch(void* const* d_in, const int* in_sizes, int n_in,
                              void* d_out, int out_size, void* d_ws, size_t ws_size,
                              hipStream_t stream) {
  const float* x            = (const float*)d_in[0];
  const unsigned char* mask = (const unsigned char*)d_in[1];
  const float* W            = (const float*)d_in[2];
  const float* bias         = (const float*)d_in[3];
  const float* trans        = (const float*)d_in[4];
  const float* lb           = (const float*)d_in[5];
  const float* rb           = (const float*)d_in[6];

  float* out         = (float*)d_out;
  float* out_decoded = out;                              // B*T
  float* out_pot     = out + (size_t)B_ * T_;            // B*T*N
  float* out_lens    = out_pot + (size_t)B_ * T_ * N_;   // B
  float* out_trans   = out_lens + B_;                    // N*N

  const size_t bp_bytes     = (size_t)B_ * T_ * N_;          // 16,777,216
  const size_t fstate_off   = bp_bytes;
  const size_t lens_off     = fstate_off + (size_t)B_ * N_ * 4;
  const size_t states_off   = lens_off + 256;
  const size_t states_bytes = (size_t)B_ * T_ * N_ * 4;      // 67,108,864

  unsigned char* bp = (unsigned char*)d_ws;
  float* fstate     = (float*)((char*)d_ws + fstate_off);
  int*   lens_i     = (int*)((char*)d_ws + lens_off);
  float* states     = (float*)((char*)d_ws + states_off);

  bool split = (ws_size >= states_off + states_bytes);

  k_misc<<<68, 64, 0, stream>>>(mask, trans, out_lens, out_trans, lens_i);
  k_gemm<<<(B_ * T_) / 64, 256, 0, stream>>>(x, W, bias, lb, rb, out_pot);
  if (split) {
    k_fwd_states<<<B_, 64, 0, stream>>>(out_pot, trans, lens_i, states, fstate);
    k_bp<<<B_ * (T_ - 1), 64, 0, stream>>>(states, trans, bp);
  } else {
    k_fwd_fused<<<B_, 64, 0, stream>>>(out_pot, trans, lens_i, bp, fstate);
  }
  k_bwd<<<B_, 64, 0, stream>>>(bp, fstate, lens_i, out_decoded);
}

// Round 3
// 1758.743 us; speedup vs baseline: 2.7485x; 1.1450x over previous
//
#include <hip/hip_runtime.h>

#define B_ 64
#define T_ 4096
#define D_ 256
#define N_ 64

typedef float f32x16 __attribute__((ext_vector_type(16)));

// ---------------- misc: lens + trans copy ----------------
__global__ __launch_bounds__(64) void k_misc(const unsigned char* __restrict__ mask,
                                             const float* __restrict__ trans,
                                             float* __restrict__ out_lens,
                                             float* __restrict__ out_trans,
                                             int* __restrict__ lens_i) {
  int blk = blockIdx.x, lane = threadIdx.x;
  if (blk < B_) {
    int probe = (int)mask[0] + (int)mask[1] + (int)mask[2] + (int)mask[3];
    int cnt = 0;
    if (probe >= 2) {
      const unsigned char* row = mask + (size_t)blk * T_;
      for (int i = lane; i < T_; i += 64) cnt += row[i] ? 1 : 0;
    } else {
      const int* rowi = (const int*)mask + (size_t)blk * T_;
      for (int i = lane; i < T_; i += 64) cnt += rowi[i] ? 1 : 0;
    }
    #pragma unroll
    for (int off = 32; off > 0; off >>= 1) cnt += __shfl_down(cnt, off, 64);
    if (lane == 0) { out_lens[blk] = (float)cnt; lens_i[blk] = cnt; }
  } else {
    int base = (blk - B_) * 1024;
    for (int i = lane; i < 1024; i += 64) out_trans[base + i] = trans[base + i];
  }
}

// ---------------- projection: pot = x@W + b (+ boundaries) ----------------
__global__ __launch_bounds__(256, 4) void k_gemm(const float* __restrict__ x,
                                                 const float* __restrict__ W,
                                                 const float* __restrict__ bias,
                                                 const float* __restrict__ lb,
                                                 const float* __restrict__ rb,
                                                 float* __restrict__ pot) {
  int wave = (blockIdx.x * blockDim.x + threadIdx.x) >> 6;
  int wave_u = __builtin_amdgcn_readfirstlane(wave);
  int lane = threadIdx.x & 63;
  long row0 = (long)wave_u * 16;

  float bv = bias[lane];
  float lbv = lb[lane];
  float rbv = rb[lane];

  float acc[16];
  #pragma unroll
  for (int r = 0; r < 16; ++r) {
    int t = (int)((row0 + r) & (T_ - 1));
    float a = bv;
    if (t == 0)      a += lbv;
    if (t == T_ - 1) a += rbv;
    acc[r] = a;
  }

  const float* xb = x + (size_t)row0 * D_;

  #pragma unroll
  for (int c = 0; c < 4; ++c) {
    int d0 = c * 64;
    float w[64];
    #pragma unroll
    for (int k = 0; k < 64; ++k) w[k] = W[(d0 + k) * N_ + lane];
    #pragma unroll
    for (int r = 0; r < 16; ++r) {
      const f32x16* xr = reinterpret_cast<const f32x16*>(xb + r * D_ + d0);
      #pragma unroll
      for (int q = 0; q < 4; ++q) {
        f32x16 xv = xr[q];
        #pragma unroll
        for (int j = 0; j < 16; ++j) acc[r] += xv[j] * w[q * 16 + j];
      }
    }
  }

  #pragma unroll
  for (int r = 0; r < 16; ++r) pot[(row0 + r) * N_ + lane] = acc[r];
}

// ---------------- phase 1: forward values only, 4x unrolled deep prefetch ----------
// Per step: 16 ds_read_b128 -> 32 pk-add candidates -> exact max3 tree -> state.
// pot row for step t is loaded 4 steps ahead into a NAMED register (no rotation),
// so the compiler keeps 4 loads in flight (vmcnt(3)) and L3 latency is hidden.
#define FWD_STEP(TIDX, PREG)                                                      \
  {                                                                               \
    float pot_t = PREG;                                                           \
    int tp = (TIDX) + 4; if (tp > T_ - 1) tp = T_ - 1;                            \
    PREG = pb[(size_t)tp * N_ + lane];                                            \
    float m[64];                                                                  \
    _Pragma("unroll")                                                             \
    for (int g = 0; g < 16; ++g) {                                                \
      float4 s4 = st4v[g];                                                        \
      float2 ca = make_float2(s4.x, s4.y) + t2[2 * g];                            \
      float2 cb = make_float2(s4.z, s4.w) + t2[2 * g + 1];                        \
      m[4 * g + 0] = ca.x; m[4 * g + 1] = ca.y;                                   \
      m[4 * g + 2] = cb.x; m[4 * g + 3] = cb.y;                                   \
    }                                                                             \
    float r1[22];                                                                 \
    _Pragma("unroll")                                                             \
    for (int i = 0; i < 21; ++i)                                                  \
      r1[i] = fmaxf(fmaxf(m[3 * i], m[3 * i + 1]), m[3 * i + 2]);                 \
    r1[21] = m[63];                                                               \
    float r2[8];                                                                  \
    _Pragma("unroll")                                                             \
    for (int i = 0; i < 7; ++i)                                                   \
      r2[i] = fmaxf(fmaxf(r1[3 * i], r1[3 * i + 1]), r1[3 * i + 2]);              \
    r2[7] = r1[21];                                                               \
    float r3a = fmaxf(fmaxf(r2[0], r2[1]), r2[2]);                                \
    float r3b = fmaxf(fmaxf(r2[3], r2[4]), r2[5]);                                \
    float r3c = fmaxf(r2[6], r2[7]);                                              \
    float best = fmaxf(fmaxf(r3a, r3b), r3c);                                     \
    float ns = pot_t + best;                                                      \
    state = ((TIDX) < len_b) ? ns : state;                                        \
    sb[(size_t)(TIDX) * N_ + lane] = state;                                       \
    __builtin_amdgcn_wave_barrier();                                              \
    st[lane] = state;                                                             \
    __builtin_amdgcn_wave_barrier();                                              \
  }

__global__ __launch_bounds__(64, 1) void k_fwd_states(const float* __restrict__ pot,
                                                      const float* __restrict__ trans,
                                                      const int* __restrict__ lens_i,
                                                      float* __restrict__ states,
                                                      float* __restrict__ fstate) {
  int b = blockIdx.x, lane = threadIdx.x;
  __shared__ float4 st4v[16];
  float* st = (float*)st4v;

  float2 t2[32];
  #pragma unroll
  for (int p = 0; p < 32; ++p)
    t2[p] = make_float2(trans[(2 * p) * N_ + lane], trans[(2 * p + 1) * N_ + lane]);

  const float* pb = pot + (size_t)b * T_ * N_;
  float* sb = states + (size_t)b * T_ * N_;
  int len_b = lens_i[b];

  float state = pb[lane];
  st[lane] = state;
  sb[lane] = state;                      // states[t=0]
  __builtin_amdgcn_wave_barrier();

  float p0 = pb[1 * N_ + lane];
  float p1 = pb[2 * N_ + lane];
  float p2 = pb[3 * N_ + lane];
  float p3 = pb[4 * N_ + lane];

  int t = 1;
  for (; t + 3 <= T_ - 1; t += 4) {
    FWD_STEP(t + 0, p0);
    FWD_STEP(t + 1, p1);
    FWD_STEP(t + 2, p2);
    FWD_STEP(t + 3, p3);
  }
  // tail: t = 4093, 4094, 4095
  FWD_STEP(t + 0, p0);
  FWD_STEP(t + 1, p1);
  FWD_STEP(t + 2, p2);

  fstate[b * N_ + lane] = state;
}

// ---------------- phase 2: backpointers, one wave per 64-t chunk ----------------
// tcol loaded once per wave; states row is wave-uniform -> scalar loads.
// best = exact max3 tree; index = reverse equality scan (first max wins).
#define BP_CHUNK 64
__global__ __launch_bounds__(64, 2) void k_bp(const float* __restrict__ states,
                                              const float* __restrict__ trans,
                                              unsigned char* __restrict__ bp) {
  int nchunk = T_ / BP_CHUNK;
  int b = blockIdx.x / nchunk;
  int chunk = blockIdx.x - b * nchunk;
  int lane = threadIdx.x;

  float tcol[64];
  #pragma unroll
  for (int p = 0; p < 64; ++p) tcol[p] = trans[p * N_ + lane];

  int t0 = chunk * BP_CHUNK;
  int tstart = (t0 == 0) ? 1 : t0;
  int tend = t0 + BP_CHUNK;

  for (int t = tstart; t < tend; ++t) {
    const f32x16* sr = reinterpret_cast<const f32x16*>(states + ((size_t)b * T_ + (t - 1)) * N_);
    f32x16 s0 = sr[0], s1 = sr[1], s2 = sr[2], s3 = sr[3];

    float c[64];
    #pragma unroll
    for (int j = 0; j < 16; ++j) {
      c[j]      = s0[j] + tcol[j];
      c[16 + j] = s1[j] + tcol[16 + j];
      c[32 + j] = s2[j] + tcol[32 + j];
      c[48 + j] = s3[j] + tcol[48 + j];
    }

    float r1[22];
    #pragma unroll
    for (int i = 0; i < 21; ++i) r1[i] = fmaxf(fmaxf(c[3 * i], c[3 * i + 1]), c[3 * i + 2]);
    r1[21] = c[63];
    float r2[8];
    #pragma unroll
    for (int i = 0; i < 7; ++i) r2[i] = fmaxf(fmaxf(r1[3 * i], r1[3 * i + 1]), r1[3 * i + 2]);
    r2[7] = r1[21];
    float r3a = fmaxf(fmaxf(r2[0], r2[1]), r2[2]);
    float r3b = fmaxf(fmaxf(r2[3], r2[4]), r2[5]);
    float r3c = fmaxf(r2[6], r2[7]);
    float best = fmaxf(fmaxf(r3a, r3b), r3c);

    int bpi = 63;
    #pragma unroll
    for (int p = 62; p >= 0; --p) bpi = (c[p] == best) ? p : bpi;

    bp[((size_t)b * T_ + t) * N_ + lane] = (unsigned char)bpi;
  }
}

// ---------------- backtrace: serial chain with 16-deep row prefetch ----------------
__global__ __launch_bounds__(64, 1) void k_bwd(const unsigned char* __restrict__ bp,
                                               const float* __restrict__ fstate,
                                               const int* __restrict__ lens_i,
                                               float* __restrict__ decoded) {
  int b = blockIdx.x, lane = threadIdx.x;

  __shared__ float fv[64];
  __shared__ int sh_tag;
  fv[lane] = fstate[b * N_ + lane];
  __syncthreads();
  if (lane == 0) {
    float best = fv[0]; int tg = 0;
    for (int i = 1; i < 64; ++i) if (fv[i] > best) { best = fv[i]; tg = i; }
    sh_tag = tg;
  }
  __syncthreads();
  int last_tag = sh_tag;
  int len_b = lens_i[b];

  const unsigned char* bpb = bp + (size_t)b * T_ * N_;
  float* dec = decoded + (size_t)b * T_;

  int tag = last_tag;
  if (lane == 0) dec[T_ - 1] = (float)last_tag;

  const int G = 16;
  int bufA[G], bufB[G];
  const int k0 = T_ - 1;
  #pragma unroll
  for (int i = 0; i < G; ++i) bufA[i] = (int)bpb[(size_t)(k0 - i) * N_ + lane];

  const int nrows = T_ - 1;
  const int groups = nrows / G;

  for (int g = 0; g < groups; ++g) {
    int kn = k0 - G * (g + 1);
    #pragma unroll
    for (int i = 0; i < G; ++i)
      bufB[i] = (kn - i >= 1) ? (int)bpb[(size_t)(kn - i) * N_ + lane] : 0;

    int kbase = k0 - G * g;
    #pragma unroll
    for (int i = 0; i < G; ++i) {
      int k = kbase - i;
      int prev = __shfl(bufA[i], tag, 64);
      int t = k - 1;
      tag = (t < len_b - 1) ? prev : last_tag;
      if (lane == 0) dec[t] = (float)tag;
    }
    #pragma unroll
    for (int i = 0; i < G; ++i) bufA[i] = bufB[i];
  }

  int kbase = k0 - G * groups;
  #pragma unroll
  for (int i = 0; i < G; ++i) {
    int k = kbase - i;
    if (k >= 1) {
      int prev = __shfl(bufA[i], tag, 64);
      int t = k - 1;
      tag = (t < len_b - 1) ? prev : last_tag;
      if (lane == 0) dec[t] = (float)tag;
    }
  }
}

extern "C" void kernel_launch(void* const* d_in, const int* in_sizes, int n_in,
                              void* d_out, int out_size, void* d_ws, size_t ws_size,
                              hipStream_t stream) {
  const float* x            = (const float*)d_in[0];
  const unsigned char* mask = (const unsigned char*)d_in[1];
  const float* W            = (const float*)d_in[2];
  const float* bias         = (const float*)d_in[3];
  const float* trans        = (const float*)d_in[4];
  const float* lb           = (const float*)d_in[5];
  const float* rb           = (const float*)d_in[6];

  float* out         = (float*)d_out;
  float* out_decoded = out;                              // B*T
  float* out_pot     = out + (size_t)B_ * T_;            // B*T*N
  float* out_lens    = out_pot + (size_t)B_ * T_ * N_;   // B
  float* out_trans   = out_lens + B_;                    // N*N

  const size_t bp_bytes     = (size_t)B_ * T_ * N_;          // 16,777,216
  const size_t fstate_off   = bp_bytes;
  const size_t lens_off     = fstate_off + (size_t)B_ * N_ * 4;
  const size_t states_off   = lens_off + 256;
  const size_t states_bytes = (size_t)B_ * T_ * N_ * 4;      // 67,108,864

  unsigned char* bp = (unsigned char*)d_ws;
  float* fstate     = (float*)((char*)d_ws + fstate_off);
  int*   lens_i     = (int*)((char*)d_ws + lens_off);
  float* states     = (float*)((char*)d_ws + states_off);

  k_misc<<<68, 64, 0, stream>>>(mask, trans, out_lens, out_trans, lens_i);
  k_gemm<<<(B_ * T_) / 64, 256, 0, stream>>>(x, W, bias, lb, rb, out_pot);
  k_fwd_states<<<B_, 64, 0, stream>>>(out_pot, trans, lens_i, states, fstate);
  k_bp<<<B_ * (T_ / BP_CHUNK), 64, 0, stream>>>(states, trans, bp);
  k_bwd<<<B_, 64, 0, stream>>>(bp, fstate, lens_i, out_decoded);
}